// Round 3
// baseline (135.337 us; speedup 1.0000x reference)
//
#include <hip/hip_runtime.h>

// Relation Graph Attention (RGAT), MI355X. v3.
// R=3, B=2, N=2048, CIN=256, NH=4, D=64.
//  K0    : W -> Wt bf16 [r][o][k]
//  K0out : out = broadcast(xs @ W_out) across heads   (residual init)
//  K1    : hs = xs @ W[r] (MFMA); epilogue: ei/ej (prescaled log2e) + V in
//          MFMA-B-fragment-tiled layout
//  K2    : per (r,b,itile16): full-j pass, reg-staged adj -> swizzled LDS,
//          2-deep pipeline w/ raw s_barrier (no vmcnt drain), P=adj*exp2(lrelu),
//          P@V MFMA, in-kernel normalize, atomicAdd into out.

constexpr int R_ = 3, B_ = 2, N_ = 2048, CIN_ = 256, NH_ = 4, D_ = 64, NHD_ = 256;
constexpr int IT2_ = 16;               // i rows per K2 block
constexpr int BK2_ = 128;              // j per LDS stage
constexpr int NST2_ = N_ / BK2_;       // 16 stages
constexpr float LEAKY = 0.1f;
constexpr float LOG2E = 1.4426950408889634f;

typedef float f32x4 __attribute__((ext_vector_type(4)));
typedef __bf16 bf16x8 __attribute__((ext_vector_type(8)));

// workspace layout (bytes)
constexpr size_t OFF_WT  = 0;                                      // ushort [R][NHD][CIN]
constexpr size_t SZ_WT   = (size_t)R_ * NHD_ * CIN_ * 2;
constexpr size_t OFF_VT  = OFF_WT + SZ_WT;                         // ushort, frag-tiled
constexpr size_t SZ_VT   = (size_t)R_ * B_ * NH_ * D_ * N_ * 2;
constexpr size_t OFF_EI  = OFF_VT + SZ_VT;                         // float [R][B][NH][N] (log2e-scaled)
constexpr size_t SZ_E    = (size_t)R_ * B_ * NH_ * N_ * 4;
constexpr size_t OFF_EJ  = OFF_EI + SZ_E;

__device__ __forceinline__ unsigned short f2bf_bits(float f) {
    __bf16 b = (__bf16)f;
    return __builtin_bit_cast(unsigned short, b);
}

// ---------------- K0: transpose+cast W -> Wt bf16 [r][o][k] ----------------
__global__ void k0_wt(const float* __restrict__ W, unsigned short* __restrict__ Wt) {
    int of = blockIdx.x * 256 + threadIdx.x;       // 0..196607
    int r = of >> 16;
    int rem = of & 65535;
    int o = rem >> 8;
    int k = rem & 255;
    float v = W[((size_t)(r * CIN_ + k)) * NHD_ + o];
    Wt[of] = f2bf_bits(v);
}

// ---------------- K0out: out[b][n][h*64+d] = (xs @ W_out)[b][n][d] ----------------
__global__ __launch_bounds__(256) void k0_out(const float* __restrict__ xs,
                                              const float* __restrict__ Wout,
                                              float* __restrict__ out) {
    int flat_row = blockIdx.x * 4 + (threadIdx.x >> 6);   // 0..4095 = b*N+n
    int d = threadIdx.x & 63;
    const float* xrow = xs + (size_t)flat_row * CIN_;
    float acc = 0.f;
#pragma unroll 8
    for (int k = 0; k < CIN_; ++k)
        acc += xrow[k] * Wout[k * D_ + d];
    float* o = out + (size_t)flat_row * NHD_ + d;
    o[0] = acc; o[64] = acc; o[128] = acc; o[192] = acc;
}

// ---------------- K1: hs GEMM + ei/ej + vt2 fragment-tiled store ----------------
// grid: R*B*(N/64) = 192 blocks, 256 threads
__global__ __launch_bounds__(256) void k1_hs(const float* __restrict__ xs,
                                             const unsigned short* __restrict__ Wt,
                                             const float* __restrict__ al,
                                             const float* __restrict__ ar,
                                             unsigned short* __restrict__ Vt,
                                             float* __restrict__ ei,
                                             float* __restrict__ ej) {
    __shared__ unsigned short lds[64][NHD_ + 8];

    int x = blockIdx.x;
    int itile = x & 31;
    int b = (x >> 5) & 1;
    int r = x >> 6;
    int tid = threadIdx.x;
    int l = tid & 63;
    int w = tid >> 6;
    int l15 = l & 15;
    int lg = l >> 4;
    int n0 = itile * 64;

    const float* xrow = xs + ((size_t)(b * N_ + n0 + w * 16 + l15)) * CIN_;
    const unsigned short* wt_base = Wt + (size_t)r * NHD_ * CIN_;

    f32x4 acc[16] = {};

#pragma unroll
    for (int ks = 0; ks < 8; ++ks) {
        int k8 = ks * 32 + lg * 8;
        float4 x0 = *(const float4*)(xrow + k8);
        float4 x1 = *(const float4*)(xrow + k8 + 4);
        bf16x8 a;
        a[0] = (__bf16)x0.x; a[1] = (__bf16)x0.y; a[2] = (__bf16)x0.z; a[3] = (__bf16)x0.w;
        a[4] = (__bf16)x1.x; a[5] = (__bf16)x1.y; a[6] = (__bf16)x1.z; a[7] = (__bf16)x1.w;
#pragma unroll
        for (int nf = 0; nf < 16; ++nf) {
            bf16x8 bf = *(const bf16x8*)(wt_base + ((size_t)(nf * 16 + l15)) * CIN_ + k8);
            acc[nf] = __builtin_amdgcn_mfma_f32_16x16x32_bf16(a, bf, acc[nf], 0, 0, 0);
        }
    }

    // --- ei/ej epilogue (log2e-prescaled) ---
    float alv[4], arv[4];
#pragma unroll
    for (int q = 0; q < 4; ++q) {
        alv[q] = al[r * D_ + q * 16 + l15];
        arv[q] = ar[r * D_ + q * 16 + l15];
    }
#pragma unroll
    for (int h = 0; h < NH_; ++h) {
#pragma unroll
        for (int reg = 0; reg < 4; ++reg) {
            float pi = 0.f, pj = 0.f;
#pragma unroll
            for (int q = 0; q < 4; ++q) {
                float v = acc[4 * h + q][reg];
                pi += v * alv[q];
                pj += v * arv[q];
            }
#pragma unroll
            for (int m = 1; m < 16; m <<= 1) {
                pi += __shfl_xor(pi, m, 64);
                pj += __shfl_xor(pj, m, 64);
            }
            if (l15 == 0) {
                int i = n0 + w * 16 + lg * 4 + reg;
                size_t eoff = ((size_t)((r * B_ + b) * NH_ + h)) * N_ + i;
                ei[eoff] = pi * LOG2E;
                ej[eoff] = pj * LOG2E;
            }
        }
    }

    // --- V store in MFMA-B-fragment tile order via LDS transpose ---
#pragma unroll
    for (int nf = 0; nf < 16; ++nf)
#pragma unroll
        for (int reg = 0; reg < 4; ++reg) {
            int row = w * 16 + lg * 4 + reg;       // local n
            int col = nf * 16 + l15;               // h*64+d
            lds[row][col] = f2bf_bits(acc[nf][reg]);
        }
    __syncthreads();

#pragma unroll
    for (int it = 0; it < 16; ++it) {
        int flat = it * 256 + tid;                 // 0..4095
        int e4  = flat & 1;
        int ll  = (flat >> 1) & 63;
        int nf  = (flat >> 7) & 3;
        int hh  = (flat >> 9) & 3;
        int jtl = (flat >> 11) & 1;
        int c = hh * 64 + nf * 16 + (ll & 15);
        int nb = jtl * 32 + ((ll >> 4) * 8) + e4 * 4;
        ushort4 v;
        v.x = lds[nb + 0][c];
        v.y = lds[nb + 1][c];
        v.z = lds[nb + 2][c];
        v.w = lds[nb + 3][c];
        size_t dst = ((size_t)((r * B_ + b) * NH_ + hh)) * (size_t)(D_ * N_)
                   + ((size_t)((itile * 2 + jtl) * 4 + nf) * 64 + ll) * 8 + e4 * 4;
        *(ushort4*)(Vt + dst) = v;
    }
}

// ---------------- K2: masked-exp attention, P@V, in-kernel normalize ----------------
// grid: R*B*(N/16) = 768 blocks of 256 threads (4 waves = 4 heads)
__global__ __launch_bounds__(256) void k2_attn(const float* __restrict__ adjs,
                                               const unsigned short* __restrict__ vt2,
                                               const float* __restrict__ ei,
                                               const float* __restrict__ ej,
                                               float* __restrict__ out) {
    __shared__ __align__(16) float adj_lds[2][IT2_ * BK2_];   // 2 x 8KB, XOR-swizzled

    int x = blockIdx.x;
    int itile = x & 127;
    int b = (x >> 7) & 1;
    int r = x >> 8;
    int tid = threadIdx.x;
    int l = tid & 63;
    int w = tid >> 6;                      // head
    int l15 = l & 15;
    int lg = l >> 4;
    int i0 = itile * IT2_;

    const float* adj_base = adjs + ((size_t)(r * B_ + b)) * N_ * N_ + (size_t)i0 * N_;
    const float* ejb = ej + ((size_t)((r * B_ + b) * NH_ + w)) * N_;
    float eiv = ei[((size_t)((r * B_ + b) * NH_ + w)) * N_ + i0 + l15];
    const unsigned short* vtb = vt2 + ((size_t)((r * B_ + b) * NH_ + w)) * (size_t)(D_ * N_);

    // staging geometry: thread covers 2 granules (16B) per stage, rows r0 and r0+8
    int r0 = tid >> 5, gc = tid & 31;
    const float* gs0 = adj_base + (size_t)r0 * N_ + gc * 4;
    const float* gs1 = adj_base + (size_t)(r0 + 8) * N_ + gc * 4;
    int wo0 = (r0 * 32 + (gc ^ (r0 & 7))) * 4;          // swizzled LDS float offset
    int wo1 = ((r0 + 8) * 32 + (gc ^ ((r0 + 8) & 7))) * 4;

    float* bufE = &adj_lds[0][0];
    float* bufO = &adj_lds[1][0];

    f32x4 acc[4] = {};
    float dsum = 0.f;
    int rx = l15 & 7;

    auto compute = [&](const float* __restrict__ buf, int st) {
        const float* rowp = buf + l15 * BK2_;
#pragma unroll
        for (int sub = 0; sub < 4; ++sub) {
            int jc = st * BK2_ + sub * 32;
            float4 e0 = *(const float4*)(ejb + jc + lg * 8);
            float4 e1 = *(const float4*)(ejb + jc + lg * 8 + 4);
            int g0 = sub * 8 + 2 * lg;
            float4 a0 = *(const float4*)(rowp + ((g0 ^ rx) << 2));
            float4 a1 = *(const float4*)(rowp + (((g0 + 1) ^ rx) << 2));
            float ev[8] = {e0.x, e0.y, e0.z, e0.w, e1.x, e1.y, e1.z, e1.w};
            float av[8] = {a0.x, a0.y, a0.z, a0.w, a1.x, a1.y, a1.z, a1.w};
            bf16x8 af;
#pragma unroll
            for (int e = 0; e < 8; ++e) {
                float t = eiv + ev[e];
                float lr = fmaxf(t, LEAKY * t);
                float p = av[e] * __builtin_amdgcn_exp2f(lr);
                dsum += p;
                af[e] = (__bf16)p;
            }
            int jt = st * 4 + sub;
#pragma unroll
            for (int nf = 0; nf < 4; ++nf) {
                bf16x8 bf = *(const bf16x8*)(vtb + ((size_t)(jt * 4 + nf) * 64 + l) * 8);
                acc[nf] = __builtin_amdgcn_mfma_f32_16x16x32_bf16(af, bf, acc[nf], 0, 0, 0);
            }
        }
    };

    // prologue: load stages 0,1; stage 0 -> bufE
    float4 rA0 = *(const float4*)(gs0);
    float4 rA1 = *(const float4*)(gs1);
    float4 rB0 = *(const float4*)(gs0 + BK2_);
    float4 rB1 = *(const float4*)(gs1 + BK2_);
    *(float4*)(bufE + wo0) = rA0;
    *(float4*)(bufE + wo1) = rA1;
    asm volatile("s_waitcnt lgkmcnt(0)" ::: "memory");
    __builtin_amdgcn_s_barrier();

    for (int st2 = 0; st2 < NST2_ / 2; ++st2) {
        int st = st2 * 2;
        // even stage: compute st from bufE; RB holds st+1; prefetch st+2 -> RA
        if (st + 2 < NST2_) {
            rA0 = *(const float4*)(gs0 + (st + 2) * BK2_);
            rA1 = *(const float4*)(gs1 + (st + 2) * BK2_);
        }
        compute(bufE, st);
        *(float4*)(bufO + wo0) = rB0;
        *(float4*)(bufO + wo1) = rB1;
        asm volatile("s_waitcnt lgkmcnt(0)" ::: "memory");
        __builtin_amdgcn_s_barrier();
        // odd stage: compute st+1 from bufO; RA holds st+2; prefetch st+3 -> RB
        if (st + 3 < NST2_) {
            rB0 = *(const float4*)(gs0 + (st + 3) * BK2_);
            rB1 = *(const float4*)(gs1 + (st + 3) * BK2_);
        }
        compute(bufO, st + 1);
        if (st + 2 < NST2_) {
            *(float4*)(bufE + wo0) = rA0;
            *(float4*)(bufE + wo1) = rA1;
        }
        asm volatile("s_waitcnt lgkmcnt(0)" ::: "memory");
        __builtin_amdgcn_s_barrier();
    }

    // --- denominator: all 4 lane-groups of a row ---
    float d0 = dsum;
    d0 += __shfl_xor(d0, 16, 64);
    d0 += __shfl_xor(d0, 32, 64);
    float iv[4];
#pragma unroll
    for (int reg = 0; reg < 4; ++reg) {
        float dr = __shfl(d0, lg * 4 + reg, 64);
        iv[reg] = dr > 0.f ? 1.0f / dr : 0.f;
    }

    // --- normalize + accumulate into out ---
    float* ob = out + ((size_t)(b * N_ + i0)) * NHD_ + w * 64;
#pragma unroll
    for (int nf = 0; nf < 4; ++nf)
#pragma unroll
        for (int reg = 0; reg < 4; ++reg)
            atomicAdd(ob + (size_t)(lg * 4 + reg) * NHD_ + nf * 16 + l15,
                      acc[nf][reg] * iv[reg]);
}

extern "C" void kernel_launch(void* const* d_in, const int* in_sizes, int n_in,
                              void* d_out, int out_size, void* d_ws, size_t ws_size,
                              hipStream_t stream) {
    const float* xs   = (const float*)d_in[0];
    const float* adjs = (const float*)d_in[1];
    const float* W    = (const float*)d_in[2];
    const float* al   = (const float*)d_in[3];
    const float* ar   = (const float*)d_in[4];
    const float* Wout = (const float*)d_in[5];
    float* out = (float*)d_out;

    char* ws = (char*)d_ws;
    unsigned short* Wt = (unsigned short*)(ws + OFF_WT);
    unsigned short* Vt = (unsigned short*)(ws + OFF_VT);
    float* ei  = (float*)(ws + OFF_EI);
    float* ej  = (float*)(ws + OFF_EJ);

    k0_wt<<<dim3((R_ * NHD_ * CIN_) / 256), dim3(256), 0, stream>>>(W, Wt);
    k0_out<<<dim3(B_ * N_ / 4), dim3(256), 0, stream>>>(xs, Wout, out);
    k1_hs<<<dim3(R_ * B_ * (N_ / 64)), dim3(256), 0, stream>>>(xs, Wt, al, ar, Vt, ei, ej);
    k2_attn<<<dim3(R_ * B_ * (N_ / IT2_)), dim3(256), 0, stream>>>(adjs, Vt, ei, ej, out);
}

// Round 4
// 108.908 us; speedup vs baseline: 1.2427x; 1.2427x over previous
//
#include <hip/hip_runtime.h>

// Relation Graph Attention (RGAT), MI355X. v4.
// R=3, B=2, N=2048, CIN=256, NH=4, D=64.
//  K0    : W -> Wt bf16 [r][o][k]
//  K0out : out = broadcast(xs @ W_out) across heads   (residual init)
//  K1    : per (r,b,itile64,head): hs-tile = xs @ W[r][:,head] (MFMA);
//          epilogue: ei/ej (log2e-prescaled) + V in MFMA-B-frag-tiled layout
//  K2    : per (r,b,itile16): 8 waves = 4 heads x 2 j-halves; reg-staged adj ->
//          swizzled LDS (2-deep pipeline, raw s_barrier, no vmcnt drain);
//          P=adj*exp2(lrelu), P@V MFMA, den via ones-MFMA, block-level den
//          exchange, cross-q merge in LDS, atomicAdd into out.

constexpr int R_ = 3, B_ = 2, N_ = 2048, CIN_ = 256, NH_ = 4, D_ = 64, NHD_ = 256;
constexpr int IT2_ = 16;               // i rows per K2 block
constexpr int BK2_ = 128;              // j per half-stage per wave
constexpr int NST2_ = 1024 / BK2_;     // 8 superstages (each covers 128 j in both halves)
constexpr float LEAKY = 0.1f;
constexpr float LOG2E = 1.4426950408889634f;

typedef float f32x4 __attribute__((ext_vector_type(4)));
typedef __bf16 bf16x8 __attribute__((ext_vector_type(8)));

// workspace layout (bytes)
constexpr size_t OFF_WT  = 0;                                      // ushort [R][NHD][CIN]
constexpr size_t SZ_WT   = (size_t)R_ * NHD_ * CIN_ * 2;
constexpr size_t OFF_VT  = OFF_WT + SZ_WT;                         // ushort, frag-tiled
constexpr size_t SZ_VT   = (size_t)R_ * B_ * NH_ * D_ * N_ * 2;
constexpr size_t OFF_EI  = OFF_VT + SZ_VT;                         // float [R][B][NH][N] (log2e-scaled)
constexpr size_t SZ_E    = (size_t)R_ * B_ * NH_ * N_ * 4;
constexpr size_t OFF_EJ  = OFF_EI + SZ_E;

__device__ __forceinline__ unsigned short f2bf_bits(float f) {
    __bf16 b = (__bf16)f;
    return __builtin_bit_cast(unsigned short, b);
}

// ---------------- K0: transpose+cast W -> Wt bf16 [r][o][k] ----------------
__global__ void k0_wt(const float* __restrict__ W, unsigned short* __restrict__ Wt) {
    int of = blockIdx.x * 256 + threadIdx.x;       // 0..196607
    int r = of >> 16;
    int rem = of & 65535;
    int o = rem >> 8;
    int k = rem & 255;
    float v = W[((size_t)(r * CIN_ + k)) * NHD_ + o];
    Wt[of] = f2bf_bits(v);
}

// ---------------- K0out: out[b][n][h*64+d] = (xs @ W_out)[b][n][d] ----------------
__global__ __launch_bounds__(256) void k0_out(const float* __restrict__ xs,
                                              const float* __restrict__ Wout,
                                              float* __restrict__ out) {
    int flat_row = blockIdx.x * 4 + (threadIdx.x >> 6);   // 0..4095 = b*N+n
    int d = threadIdx.x & 63;
    const float* xrow = xs + (size_t)flat_row * CIN_;
    float acc = 0.f;
#pragma unroll 8
    for (int k = 0; k < CIN_; ++k)
        acc += xrow[k] * Wout[k * D_ + d];
    float* o = out + (size_t)flat_row * NHD_ + d;
    o[0] = acc; o[64] = acc; o[128] = acc; o[192] = acc;
}

// ---------------- K1: per-head hs GEMM + ei/ej + frag-tiled V store ----------------
// grid: R*B*32*4 = 768 blocks, 256 threads (4 waves x 16 rows); head = blockIdx&3
__global__ __launch_bounds__(256) void k1_hs(const float* __restrict__ xs,
                                             const unsigned short* __restrict__ Wt,
                                             const float* __restrict__ al,
                                             const float* __restrict__ ar,
                                             unsigned short* __restrict__ Vt,
                                             float* __restrict__ ei,
                                             float* __restrict__ ej) {
    __shared__ unsigned short lds2[64][72];

    int x = blockIdx.x;
    int ct = x & 3;                        // head
    int itile = (x >> 2) & 31;
    int b = (x >> 7) & 1;
    int r = x >> 8;
    int tid = threadIdx.x;
    int l = tid & 63;
    int w = tid >> 6;
    int l15 = l & 15;
    int lg = l >> 4;
    int n0 = itile * 64;

    const float* xrow = xs + ((size_t)(b * N_ + n0 + w * 16 + l15)) * CIN_;
    const unsigned short* wt_base = Wt + ((size_t)r * NHD_ + ct * 64) * CIN_;

    f32x4 acc[4] = {};

#pragma unroll
    for (int ks = 0; ks < 8; ++ks) {
        int k8 = ks * 32 + lg * 8;
        float4 x0 = *(const float4*)(xrow + k8);
        float4 x1 = *(const float4*)(xrow + k8 + 4);
        bf16x8 a;
        a[0] = (__bf16)x0.x; a[1] = (__bf16)x0.y; a[2] = (__bf16)x0.z; a[3] = (__bf16)x0.w;
        a[4] = (__bf16)x1.x; a[5] = (__bf16)x1.y; a[6] = (__bf16)x1.z; a[7] = (__bf16)x1.w;
#pragma unroll
        for (int nf = 0; nf < 4; ++nf) {
            bf16x8 bf = *(const bf16x8*)(wt_base + ((size_t)(nf * 16 + l15)) * CIN_ + k8);
            acc[nf] = __builtin_amdgcn_mfma_f32_16x16x32_bf16(a, bf, acc[nf], 0, 0, 0);
        }
    }

    // --- ei/ej epilogue (log2e-prescaled); al/ar shared across heads ---
    float alv[4], arv[4];
#pragma unroll
    for (int nf = 0; nf < 4; ++nf) {
        alv[nf] = al[r * D_ + nf * 16 + l15];
        arv[nf] = ar[r * D_ + nf * 16 + l15];
    }
#pragma unroll
    for (int reg = 0; reg < 4; ++reg) {
        float pi = 0.f, pj = 0.f;
#pragma unroll
        for (int nf = 0; nf < 4; ++nf) {
            float v = acc[nf][reg];
            pi += v * alv[nf];
            pj += v * arv[nf];
        }
#pragma unroll
        for (int m = 1; m < 16; m <<= 1) {
            pi += __shfl_xor(pi, m, 64);
            pj += __shfl_xor(pj, m, 64);
        }
        if (l15 == 0) {
            int i = n0 + w * 16 + lg * 4 + reg;
            size_t eoff = ((size_t)((r * B_ + b) * NH_ + ct)) * N_ + i;
            ei[eoff] = pi * LOG2E;
            ej[eoff] = pj * LOG2E;
        }
    }

    // --- V store in MFMA-B-fragment tile order via LDS transpose ---
#pragma unroll
    for (int nf = 0; nf < 4; ++nf)
#pragma unroll
        for (int reg = 0; reg < 4; ++reg)
            lds2[w * 16 + lg * 4 + reg][nf * 16 + l15] = f2bf_bits(acc[nf][reg]);
    __syncthreads();

    size_t hb = ((size_t)((r * B_ + b) * NH_ + ct)) * (size_t)(D_ * N_) + (size_t)itile * 4096;
#pragma unroll
    for (int it = 0; it < 4; ++it) {
        int f4 = it * 256 + tid;               // 0..1023 (ushort4 index)
        int e4  = f4 & 1;
        int ll  = (f4 >> 1) & 63;
        int nf  = (f4 >> 7) & 3;
        int jtl = f4 >> 9;
        int col = nf * 16 + (ll & 15);
        int rowb = jtl * 32 + ((ll >> 4) * 8) + e4 * 4;
        ushort4 v;
        v.x = lds2[rowb + 0][col];
        v.y = lds2[rowb + 1][col];
        v.z = lds2[rowb + 2][col];
        v.w = lds2[rowb + 3][col];
        *(ushort4*)(Vt + hb + (size_t)f4 * 4) = v;
    }
}

// ---------------- K2: masked-exp attention, P@V, in-kernel normalize ----------------
// grid: R*B*(N/16) = 768 blocks of 512 threads (8 waves: h = w&3, q = w>>2)
__global__ __launch_bounds__(512, 6) void k2_attn(const float* __restrict__ adjs,
                                                  const unsigned short* __restrict__ vt2,
                                                  const float* __restrict__ ei,
                                                  const float* __restrict__ ej,
                                                  float* __restrict__ out) {
    __shared__ __align__(16) float adj_lds[2][IT2_ * 256];   // 2 x 16 KB, XOR-swizzled
    __shared__ float den_sh[2][NH_][IT2_];

    int x = blockIdx.x;
    x = (x & 7) * 96 + (x >> 3);           // XCD-chunked swizzle (768 = 8*96, bijective)
    int itile = x & 127;
    int b = (x >> 7) & 1;
    int r = x >> 8;
    int tid = threadIdx.x;
    int l = tid & 63;
    int w = tid >> 6;
    int h = w & 3;                         // head
    int q = w >> 2;                        // j-half
    int l15 = l & 15;
    int lg = l >> 4;
    int rx = l15 & 7;
    int i0 = itile * IT2_;

    const float* adj_base = adjs + ((size_t)(r * B_ + b)) * N_ * N_ + (size_t)i0 * N_;
    const float* ejb = ej + ((size_t)((r * B_ + b) * NH_ + h)) * N_ + q * 1024;
    float eiv = ei[((size_t)((r * B_ + b) * NH_ + h)) * N_ + i0 + l15];
    const unsigned short* vtb = vt2 + ((size_t)((r * B_ + b) * NH_ + h)) * (size_t)(D_ * N_);

    // staging geometry: 512 threads x 2 float4 cover 16 rows x 256 cols
    // (cols 0..127 = half0 j=s*128.., cols 128..255 = half1 j=1024+s*128..)
    int cg = tid & 63;                     // granule within row (0..63)
    int r0 = tid >> 6;                     // row (0..7); second load row+8
    int half = cg >> 5, c32 = cg & 31;
    const float* gs0 = adj_base + (size_t)r0 * N_ + half * 1024 + c32 * 4;
    const float* gs1 = gs0 + 8 * N_;
    int wo0 = r0 * 256 + ((cg ^ (r0 & 7)) << 2);
    int wo1 = (r0 + 8) * 256 + ((cg ^ (r0 & 7)) << 2);

    float* bufE = &adj_lds[0][0];
    float* bufO = &adj_lds[1][0];

    // ones B-frag (col 0) for den-via-MFMA
    bf16x8 onesb;
    {
        __bf16 o1 = (l15 == 0) ? (__bf16)1.0f : (__bf16)0.0f;
#pragma unroll
        for (int e = 0; e < 8; ++e) onesb[e] = o1;
    }

    f32x4 acc[4] = {};
    f32x4 accD = {};

    auto compute = [&](const float* __restrict__ buf, int s) {
        const float* rp = buf + l15 * 256;
#pragma unroll
        for (int sub = 0; sub < 4; ++sub) {
            int jl = s * BK2_ + sub * 32;                   // within this wave's half
            float4 e0 = *(const float4*)(ejb + jl + lg * 8);
            float4 e1 = *(const float4*)(ejb + jl + lg * 8 + 4);
            int gb = q * 32 + sub * 8 + 2 * lg;
            float4 a0 = *(const float4*)(rp + ((gb ^ rx) << 2));
            float4 a1 = *(const float4*)(rp + (((gb + 1) ^ rx) << 2));
            float ev[8] = {e0.x, e0.y, e0.z, e0.w, e1.x, e1.y, e1.z, e1.w};
            float av[8] = {a0.x, a0.y, a0.z, a0.w, a1.x, a1.y, a1.z, a1.w};
            bf16x8 af;
#pragma unroll
            for (int e = 0; e < 8; ++e) {
                float t = eiv + ev[e];
                float lr = fmaxf(t, LEAKY * t);               // lrelu (log2-scaled)
                float p = av[e] * __builtin_amdgcn_exp2f(lr); // adj in {0,1}: mask via mul
                af[e] = (__bf16)p;
            }
            accD = __builtin_amdgcn_mfma_f32_16x16x32_bf16(af, onesb, accD, 0, 0, 0);
            int jt = q * 32 + s * 4 + sub;
#pragma unroll
            for (int nf = 0; nf < 4; ++nf) {
                bf16x8 bf = *(const bf16x8*)(vtb + ((size_t)(jt * 4 + nf) * 64 + l) * 8);
                acc[nf] = __builtin_amdgcn_mfma_f32_16x16x32_bf16(af, bf, acc[nf], 0, 0, 0);
            }
        }
    };

    // prologue: load stages 0,1; stage 0 -> bufE
    float4 rA0 = *(const float4*)(gs0);
    float4 rA1 = *(const float4*)(gs1);
    float4 rB0 = *(const float4*)(gs0 + BK2_);
    float4 rB1 = *(const float4*)(gs1 + BK2_);
    *(float4*)(bufE + wo0) = rA0;
    *(float4*)(bufE + wo1) = rA1;
    asm volatile("s_waitcnt lgkmcnt(0)" ::: "memory");
    __builtin_amdgcn_s_barrier();

    for (int s2 = 0; s2 < NST2_ / 2; ++s2) {
        int s = s2 * 2;
        if (s + 2 < NST2_) {
            rA0 = *(const float4*)(gs0 + (s + 2) * BK2_);
            rA1 = *(const float4*)(gs1 + (s + 2) * BK2_);
        }
        compute(bufE, s);
        *(float4*)(bufO + wo0) = rB0;
        *(float4*)(bufO + wo1) = rB1;
        asm volatile("s_waitcnt lgkmcnt(0)" ::: "memory");
        __builtin_amdgcn_s_barrier();
        if (s + 3 < NST2_) {
            rB0 = *(const float4*)(gs0 + (s + 3) * BK2_);
            rB1 = *(const float4*)(gs1 + (s + 3) * BK2_);
        }
        compute(bufO, s + 1);
        if (s + 2 < NST2_) {
            *(float4*)(bufE + wo0) = rA0;
            *(float4*)(bufE + wo1) = rA1;
        }
        asm volatile("s_waitcnt lgkmcnt(0)" ::: "memory");
        __builtin_amdgcn_s_barrier();
    }

    // --- block-level denominator: accD col 0 lives in lanes l15==0 ---
    if (l15 == 0) {
#pragma unroll
        for (int reg = 0; reg < 4; ++reg)
            den_sh[q][h][lg * 4 + reg] = accD[reg];
    }
    __syncthreads();
    float inv[4];
#pragma unroll
    for (int reg = 0; reg < 4; ++reg) {
        float dd = den_sh[0][h][lg * 4 + reg] + den_sh[1][h][lg * 4 + reg];
        inv[reg] = dd > 0.f ? 1.0f / dd : 0.f;
    }

    // --- cross-q merge in LDS (reuse adj_lds), then one atomicAdd per elem ---
    float* accsh = &adj_lds[0][0];         // [4 heads][16 rows][64 cols] = 16 KB
    if (q == 1) {
#pragma unroll
        for (int nf = 0; nf < 4; ++nf)
#pragma unroll
            for (int reg = 0; reg < 4; ++reg)
                accsh[(h * 16 + lg * 4 + reg) * 64 + nf * 16 + l15] = acc[nf][reg] * inv[reg];
    }
    __syncthreads();
    if (q == 0) {
        float* ob = out + ((size_t)(b * N_ + i0)) * NHD_ + h * 64;
#pragma unroll
        for (int nf = 0; nf < 4; ++nf)
#pragma unroll
            for (int reg = 0; reg < 4; ++reg) {
                float v = acc[nf][reg] * inv[reg]
                        + accsh[(h * 16 + lg * 4 + reg) * 64 + nf * 16 + l15];
                atomicAdd(ob + (size_t)(lg * 4 + reg) * NHD_ + nf * 16 + l15, v);
            }
    }
}

extern "C" void kernel_launch(void* const* d_in, const int* in_sizes, int n_in,
                              void* d_out, int out_size, void* d_ws, size_t ws_size,
                              hipStream_t stream) {
    const float* xs   = (const float*)d_in[0];
    const float* adjs = (const float*)d_in[1];
    const float* W    = (const float*)d_in[2];
    const float* al   = (const float*)d_in[3];
    const float* ar   = (const float*)d_in[4];
    const float* Wout = (const float*)d_in[5];
    float* out = (float*)d_out;

    char* ws = (char*)d_ws;
    unsigned short* Wt = (unsigned short*)(ws + OFF_WT);
    unsigned short* Vt = (unsigned short*)(ws + OFF_VT);
    float* ei  = (float*)(ws + OFF_EI);
    float* ej  = (float*)(ws + OFF_EJ);

    k0_wt<<<dim3((R_ * NHD_ * CIN_) / 256), dim3(256), 0, stream>>>(W, Wt);
    k0_out<<<dim3(B_ * N_ / 4), dim3(256), 0, stream>>>(xs, Wout, out);
    k1_hs<<<dim3(R_ * B_ * 32 * 4), dim3(256), 0, stream>>>(xs, Wt, al, ar, Vt, ei, ej);
    k2_attn<<<dim3(R_ * B_ * (N_ / IT2_)), dim3(512), 0, stream>>>(adjs, Vt, ei, ej, out);
}